// Round 9
// baseline (35.400 us; speedup 1.0000x reference)
//
#include <hip/hip_runtime.h>
#include <math.h>

// DegradedBicycleRollout: b=512, l=64, h=80, state=12.
// R9: break the serial chain's trans dependency. Key identity: vx^2+vy^2 =
// speed2^2 (cos^2+sin^2=1), so speed chain is s' = sqrt(s2^2+1e-6),
// s2 = max(s+acc*dt,0) -- sin/cos/vx/vy move OFF the critical path (they only
// feed outputs; px/py are fma accumulators). R8 post-mortem: compute wave
// ~1000cyc/step w/ 1 wave/SIMD == trans latency on chain (sqrt<-vx,vy<-sin/cos).
// Also: tan -> odd poly (|d|<=0.75), writer issues ctl loads BEFORE flush
// stores (counted vmcnt, no store drain), writer barrier = lgkm-only s_barrier
// (stores stay in flight across chunks).

#define N_B 512
#define N_L 64
#define N_H 80
#define DT_F 0.1f
#define PITCH_F4 25       // out-buf pitch: 24 used + 1 pad
#define CPITCH 7          // ctl-buf pitch: 6 used + 1 pad
#define SPC 8             // steps per chunk
#define NCH 10            // chunks
#define INV2PI 0.15915494309189535f

__device__ __forceinline__ float fast_rcp(float x) { return __builtin_amdgcn_rcpf(x); }

__device__ __forceinline__ float fast_tanh(float x) {
    const float e2 = __expf(2.0f * x);
    return (e2 - 1.0f) * fast_rcp(e2 + 1.0f);
}

__device__ __forceinline__ float fast_sigmoid(float x) {
    return fast_rcp(1.0f + __expf(-x));
}

__device__ __forceinline__ float fast_atan_small(float z) {
    // |z| <= 0.42; odd Taylor through z^9, max err ~1e-5.
    const float z2 = z * z;
    float p = 1.0f / 9.0f;
    p = fmaf(p, z2, -1.0f / 7.0f);
    p = fmaf(p, z2, 1.0f / 5.0f);
    p = fmaf(p, z2, -1.0f / 3.0f);
    p = fmaf(p, z2, 1.0f);
    return z * p;
}

__device__ __forceinline__ float fast_tan_075(float x) {
    // tan(x) on |x|<=0.75 via odd Taylor through x^13; max err ~3e-5 at edge.
    const float x2 = x * x;
    float p = 0.0035916f;            // 21844/6081075
    p = fmaf(p, x2, 0.0088632f);     // 1382/155925
    p = fmaf(p, x2, 0.0218695f);     // 62/2835
    p = fmaf(p, x2, 0.0539683f);     // 17/315
    p = fmaf(p, x2, 0.1333333f);     // 2/15
    p = fmaf(p, x2, 0.3333333f);     // 1/3
    return fmaf(p * x2, x, x);
}

struct Ctl { float delta, fb, fx, tan_d, beta, acc; };

__device__ __forceinline__ Ctl make_ctl(float u0, float u1, float u2,
                                        float steer_scale, float brake_scale,
                                        float throttle_scale, float neg_brake_lim) {
    Ctl t;
    t.delta = steer_scale * fast_tanh(u0);
    t.fb = brake_scale    * fast_sigmoid(u1);
    t.fx = throttle_scale * fast_sigmoid(u2);
    const float dc = fminf(fmaxf(t.delta, -0.75f), 0.75f);
    t.tan_d = fast_tan_075(dc);
    t.beta = fminf(fmaxf(fast_atan_small(0.45f * t.tan_d), -0.65f), 0.65f);
    t.acc = fminf(fmaxf(2.8f * t.fx - 6.5f * t.fb, neg_brake_lim), 3.0f);
    return t;
}

__global__ __launch_bounds__(128) void degraded_bicycle_rollout_kernel(
    const float* __restrict__ x0,        // [512,12]
    const float* __restrict__ controls,  // [512,64,80,3]
    const float* __restrict__ deg,       // [512,5]
    float* __restrict__ out)             // [512,64,81,12]
{
    __shared__ float4 lds4[2][N_L * PITCH_F4];   // out staging, 2 x 25.6 KB
    __shared__ float4 ldsc[2][N_L * CPITCH];     // ctl staging, 2 x 7.2 KB

    const int lane = threadIdx.x & 63;
    const int wave = threadIdx.x >> 6;        // 0 = compute, 1 = writer/loader
    const int b = blockIdx.x;                 // one b per block

    const size_t out_b = (size_t)b * 62208;   // b*64*972 floats

#define FLUSH_SLICE(FBUF, FC)                                                     \
    {                                                                             \
        const size_t obase = out_b + 12 + (size_t)(FC) * (SPC * 12);              \
        _Pragma("unroll")                                                         \
        for (int i = 0; i < 24; ++i) {                                            \
            const unsigned flat = i * 64 + lane;                                  \
            const unsigned l = flat / 24u;                                        \
            const unsigned q = flat - l * 24u;                                    \
            const float4 v = lds4[FBUF][l * PITCH_F4 + q];                        \
            *reinterpret_cast<float4*>(out + obase + (size_t)l * 972 + q * 4) = v;\
        }                                                                         \
    }

    // ctl element addressing for slot i (i*64+lane over 64 l x 6 j)
#define CTL_L(i) (((i) * 64u + (unsigned)lane) / 6u)
#define CTL_J(i) (((i) * 64u + (unsigned)lane) - CTL_L(i) * 6u)

    if (wave == 0) {
        // ================= compute persona =================
        const float* dg = deg + b * 5;
        const float steer_scale    = fmaxf(dg[0], 0.05f);
        const float brake_scale    = fmaxf(dg[1], 0.05f);
        const float throttle_scale = fmaxf(dg[2], 0.05f);
        const float friction       = fmaxf(dg[4], 0.1f);

        const float4* x0v = reinterpret_cast<const float4*>(x0 + b * 12);
        const float4 xi0 = x0v[0];
        const float4 xi1 = x0v[1];

        float px  = xi0.x;
        float py  = xi0.y;
        float psi = xi0.z;
        float vxp = xi0.w;
        float vyp = xi1.x;
        // speed chain state (identity: vx^2+vy^2 == speed2^2 after step 1)
        float s = __builtin_amdgcn_sqrtf(fmaf(vxp, vxp, fmaf(vyp, vyp, 1e-6f)));

        const float neg_brake_lim = -7.5f * friction;
        const float yaw_num = friction * 9.81f;
        const float inv_wheelbase = 1.0f / 2.8f;

        __syncthreads();   // prologue: ctl chunk 0 staged by writer

        for (int c = 0; c < NCH; ++c) {
            float4* lrow = &lds4[c & 1][lane * PITCH_F4];
            const float4* crow = &ldsc[c & 1][lane * CPITCH];

            const float4 u0 = crow[0];
            const float4 u1 = crow[1];
            const float4 u2 = crow[2];
            const float4 u3 = crow[3];
            const float4 u4 = crow[4];
            const float4 u5 = crow[5];

            // all 8 steps' control transforms up-front (independent -> fill
            // the chain's stall slots)
            const Ctl tA = make_ctl(u0.x, u0.y, u0.z, steer_scale, brake_scale, throttle_scale, neg_brake_lim);
            const Ctl tB = make_ctl(u0.w, u1.x, u1.y, steer_scale, brake_scale, throttle_scale, neg_brake_lim);
            const Ctl tC = make_ctl(u1.z, u1.w, u2.x, steer_scale, brake_scale, throttle_scale, neg_brake_lim);
            const Ctl tD = make_ctl(u2.y, u2.z, u2.w, steer_scale, brake_scale, throttle_scale, neg_brake_lim);
            const Ctl tE = make_ctl(u3.x, u3.y, u3.z, steer_scale, brake_scale, throttle_scale, neg_brake_lim);
            const Ctl tF = make_ctl(u3.w, u4.x, u4.y, steer_scale, brake_scale, throttle_scale, neg_brake_lim);
            const Ctl tG = make_ctl(u4.z, u4.w, u5.x, steer_scale, brake_scale, throttle_scale, neg_brake_lim);
            const Ctl tH = make_ctl(u5.y, u5.z, u5.w, steer_scale, brake_scale, throttle_scale, neg_brake_lim);

#define ROLL_STEP(T, RR)                                                          \
            {                                                                     \
                const float s2 = fmaxf(fmaf((T).acc, DT_F, s), 0.0f);             \
                const float raw_yaw = s2 * inv_wheelbase * (T).tan_d;             \
                const float yaw_lim = fmaxf(yaw_num * fast_rcp(fmaxf(s2, 2.0f)), 0.15f); \
                const float yaw_rate = fminf(fmaxf(raw_yaw, -1.0f), 1.0f) * yaw_lim; \
                const float psi2 = fmaf(yaw_rate, DT_F, psi);                     \
                const float ang = (psi2 + (T).beta) * INV2PI;                     \
                const float sn = __builtin_amdgcn_sinf(ang);                      \
                const float cs = __builtin_amdgcn_cosf(ang);                      \
                const float vx2 = s2 * cs;                                        \
                const float vy2 = s2 * sn;                                        \
                const float px2 = fmaf(vx2, DT_F, px);                            \
                const float py2 = fmaf(vy2, DT_F, py);                            \
                const float ax = (vx2 - vxp) * 10.0f;                             \
                const float ay = (vy2 - vyp) * 10.0f;                             \
                lrow[(RR) * 3 + 0] = make_float4(px2, py2, psi2, vx2);            \
                lrow[(RR) * 3 + 1] = make_float4(vy2, yaw_rate, ax, ay);          \
                lrow[(RR) * 3 + 2] = make_float4((T).beta, (T).delta, (T).fb, (T).fx); \
                s = __builtin_amdgcn_sqrtf(fmaf(s2, s2, 1e-6f));                  \
                px = px2; py = py2; psi = psi2; vxp = vx2; vyp = vy2;             \
            }

            ROLL_STEP(tA, 0) ROLL_STEP(tB, 1) ROLL_STEP(tC, 2) ROLL_STEP(tD, 3)
            ROLL_STEP(tE, 4) ROLL_STEP(tF, 5) ROLL_STEP(tG, 6) ROLL_STEP(tH, 7)
#undef ROLL_STEP

            __syncthreads();   // chunk c staged; ctl for c+1 staged by writer
        }
    } else {
        // ============ writer / control-loader persona ============
        // h = 0 rows (one-time)
        {
            const float4* x0v = reinterpret_cast<const float4*>(x0 + b * 12);
            const float4 xq0 = x0v[0];
            const float4 xq1 = x0v[1];
            const float4 xq2 = x0v[2];
            #pragma unroll
            for (int i = 0; i < 3; ++i) {
                const unsigned flat = i * 64 + lane;
                const unsigned l = flat / 3u;
                const unsigned q = flat - l * 3u;
                const float4 v = (q == 0) ? xq0 : (q == 1) ? xq1 : xq2;
                *reinterpret_cast<float4*>(out + out_b + (size_t)l * 972 + q * 4) = v;
            }
        }
        // prologue: stage ctl chunk 0
        {
            const size_t gbase = (size_t)b * 15360;
            float4 q0 = *reinterpret_cast<const float4*>(controls + gbase + (size_t)CTL_L(0) * 240 + CTL_J(0) * 4);
            float4 q1 = *reinterpret_cast<const float4*>(controls + gbase + (size_t)CTL_L(1) * 240 + CTL_J(1) * 4);
            float4 q2 = *reinterpret_cast<const float4*>(controls + gbase + (size_t)CTL_L(2) * 240 + CTL_J(2) * 4);
            float4 q3 = *reinterpret_cast<const float4*>(controls + gbase + (size_t)CTL_L(3) * 240 + CTL_J(3) * 4);
            float4 q4 = *reinterpret_cast<const float4*>(controls + gbase + (size_t)CTL_L(4) * 240 + CTL_J(4) * 4);
            float4 q5 = *reinterpret_cast<const float4*>(controls + gbase + (size_t)CTL_L(5) * 240 + CTL_J(5) * 4);
            ldsc[0][CTL_L(0) * CPITCH + CTL_J(0)] = q0;
            ldsc[0][CTL_L(1) * CPITCH + CTL_J(1)] = q1;
            ldsc[0][CTL_L(2) * CPITCH + CTL_J(2)] = q2;
            ldsc[0][CTL_L(3) * CPITCH + CTL_J(3)] = q3;
            ldsc[0][CTL_L(4) * CPITCH + CTL_J(4)] = q4;
            ldsc[0][CTL_L(5) * CPITCH + CTL_J(5)] = q5;
        }
        asm volatile("s_waitcnt lgkmcnt(0)" ::: "memory");
        __builtin_amdgcn_s_barrier();
        __builtin_amdgcn_sched_barrier(0);

        for (int c = 0; c < NCH; ++c) {
            // 1) issue next chunk's ctl loads FIRST (oldest in vmem queue ->
            //    the later ds_write waits a COUNTED vmcnt, not a store drain)
            float4 q0, q1, q2, q3, q4, q5;
            const bool more = (c + 1 < NCH);
            if (more) {
                const size_t gbase = (size_t)b * 15360 + (size_t)(c + 1) * 24;
                q0 = *reinterpret_cast<const float4*>(controls + gbase + (size_t)CTL_L(0) * 240 + CTL_J(0) * 4);
                q1 = *reinterpret_cast<const float4*>(controls + gbase + (size_t)CTL_L(1) * 240 + CTL_J(1) * 4);
                q2 = *reinterpret_cast<const float4*>(controls + gbase + (size_t)CTL_L(2) * 240 + CTL_J(2) * 4);
                q3 = *reinterpret_cast<const float4*>(controls + gbase + (size_t)CTL_L(3) * 240 + CTL_J(3) * 4);
                q4 = *reinterpret_cast<const float4*>(controls + gbase + (size_t)CTL_L(4) * 240 + CTL_J(4) * 4);
                q5 = *reinterpret_cast<const float4*>(controls + gbase + (size_t)CTL_L(5) * 240 + CTL_J(5) * 4);
            }
            // 2) flush chunk c-1 (24 ds_read + 24 stores; stores left in flight)
            if (c > 0) FLUSH_SLICE((c - 1) & 1, c - 1)
            // 3) ds_write next ctl (compiler emits counted vmcnt for q0..q5)
            if (more) {
                const int nb = (c + 1) & 1;
                ldsc[nb][CTL_L(0) * CPITCH + CTL_J(0)] = q0;
                ldsc[nb][CTL_L(1) * CPITCH + CTL_J(1)] = q1;
                ldsc[nb][CTL_L(2) * CPITCH + CTL_J(2)] = q2;
                ldsc[nb][CTL_L(3) * CPITCH + CTL_J(3)] = q3;
                ldsc[nb][CTL_L(4) * CPITCH + CTL_J(4)] = q4;
                ldsc[nb][CTL_L(5) * CPITCH + CTL_J(5)] = q5;
            }
            // 4) lgkm-only barrier: global stores stay in flight across chunks
            asm volatile("s_waitcnt lgkmcnt(0)" ::: "memory");
            __builtin_amdgcn_s_barrier();
            __builtin_amdgcn_sched_barrier(0);
        }
        FLUSH_SLICE((NCH - 1) & 1, NCH - 1)
    }
#undef FLUSH_SLICE
#undef CTL_L
#undef CTL_J
}

extern "C" void kernel_launch(void* const* d_in, const int* in_sizes, int n_in,
                              void* d_out, int out_size, void* d_ws, size_t ws_size,
                              hipStream_t stream) {
    (void)in_sizes; (void)n_in; (void)d_ws; (void)ws_size; (void)out_size;
    const float* x0       = (const float*)d_in[0];
    const float* controls = (const float*)d_in[1];
    const float* deg      = (const float*)d_in[2];
    float* out            = (float*)d_out;

    dim3 grid(N_B), block(128);               // 512 blocks x 2 waves
    hipLaunchKernelGGL(degraded_bicycle_rollout_kernel, grid, block, 0, stream,
                       x0, controls, deg, out);
}